// Round 5
// baseline (222.522 us; speedup 1.0000x reference)
//
#include <hip/hip_runtime.h>
#include <hip/hip_cooperative_groups.h>
#include <stdint.h>

namespace cg = cooperative_groups;

#define L_ 4096
#define S_ 256
#define D_ 512
#define NW 64  // 64-bit words per length-4096 row

static __device__ const float LN2F = 0.69314718055994530942f;

// ---------------- word-local conflict primitives (no carry-in; caller masks) ----------------
// out[t] = c[t] & ~out[t-1] within a word, assuming out[-1]=0
__device__ __forceinline__ uint64_t pass1_noc(uint64_t wp) {
    uint64_t o = wp & ~(wp << 1);
    uint64_t h = wp & (wp << 1);
    o |= (o << 2)  & h; h &= (h << 2);
    o |= (o << 4)  & h; h &= (h << 4);
    o |= (o << 8)  & h; h &= (h << 8);
    o |= (o << 16) & h; h &= (h << 16);
    o |= (o << 32) & h;
    return o;
}
// out[t] = a[t] & ~out[t-2] within a word, assuming out[-1]=out[-2]=0
__device__ __forceinline__ uint64_t pass2_noc(uint64_t ap) {
    uint64_t o = ap & ~(ap << 2);
    uint64_t h = ap & (ap << 2);
    o |= (o << 4)  & h; h &= (h << 4);
    o |= (o << 8)  & h; h &= (h << 8);
    o |= (o << 16) & h; h &= (h << 16);
    o |= (o << 32) & h;
    return o;
}

// ---------------- single cooperative kernel ----------------
__global__ __launch_bounds__(1024)
void k_all(const int* __restrict__ x, const float* __restrict__ embd,
           const float* __restrict__ w1, const float* __restrict__ b1,
           const float* __restrict__ w2, const float* __restrict__ b2,
           const float* __restrict__ w3, const float* __restrict__ b3,
           const int* __restrict__ al1, const int* __restrict__ al2, const int* __restrict__ al3,
           const float2* __restrict__ g1, const float2* __restrict__ g2, const float2* __restrict__ g3,
           float2* __restrict__ lph, float* __restrict__ entbuf, float* __restrict__ out) {
    const int tid  = threadIdx.x;
    const int lane = tid & 63;
    const int wv   = tid >> 6;     // 0..15

    // ===== Phase 0: per-position logits -> logp (one wave per position) =====
    {
        const int t = blockIdx.x * 16 + wv;       // 256 blocks x 16 waves = 4096 positions
        const int t1 = (t + 1 < L_) ? t + 1 : t;
        const int t2 = (t + 2 < L_) ? t + 2 : t;
        const int d0 = lane * 8;

        const float4* e0p = (const float4*)(embd + (size_t)x[t]  * D_ + d0);
        const float4* e1p = (const float4*)(embd + (size_t)x[t1] * D_ + d0);
        const float4* e2p = (const float4*)(embd + (size_t)x[t2] * D_ + d0);
        float4 e0a = e0p[0], e0b = e0p[1];
        float4 e1a = e1p[0], e1b = e1p[1];
        float4 e2a = e2p[0], e2b = e2p[1];
        const float4* w1p = (const float4*)(w1 + 2 * d0);
        const float4* w2p = (const float4*)(w2 + 2 * d0);
        const float4* w3p = (const float4*)(w3 + 2 * d0);

        float v0[8] = {e0a.x,e0a.y,e0a.z,e0a.w,e0b.x,e0b.y,e0b.z,e0b.w};
        float v1[8] = {e1a.x,e1a.y,e1a.z,e1a.w,e1b.x,e1b.y,e1b.z,e1b.w};
        float v2[8] = {e2a.x,e2a.y,e2a.z,e2a.w,e2b.x,e2b.y,e2b.z,e2b.w};
        float wv1[16], wv2[16], wv3[16];
        for (int q = 0; q < 4; q++) {
            float4 a = w1p[q]; wv1[4*q]=a.x; wv1[4*q+1]=a.y; wv1[4*q+2]=a.z; wv1[4*q+3]=a.w;
            float4 b = w2p[q]; wv2[4*q]=b.x; wv2[4*q+1]=b.y; wv2[4*q+2]=b.z; wv2[4*q+3]=b.w;
            float4 c = w3p[q]; wv3[4*q]=c.x; wv3[4*q+1]=c.y; wv3[4*q+2]=c.z; wv3[4*q+3]=c.w;
        }
        double a0=0,a1=0,a2=0,a3=0,a4=0,a5=0;
        #pragma unroll
        for (int j = 0; j < 8; j++) {
            float s2 = (v1[j] + v0[j]) * 0.5f;        // reference order in f32
            float s3 = ((v2[j] + v1[j]) + v0[j]) / 3.0f;
            a0 += (double)v0[j] * (double)wv1[2*j];
            a1 += (double)v0[j] * (double)wv1[2*j+1];
            a2 += (double)s2    * (double)wv2[2*j];
            a3 += (double)s2    * (double)wv2[2*j+1];
            a4 += (double)s3    * (double)wv3[2*j];
            a5 += (double)s3    * (double)wv3[2*j+1];
        }
        #pragma unroll
        for (int o = 32; o > 0; o >>= 1) {
            a0 += __shfl_xor(a0, o, 64);
            a1 += __shfl_xor(a1, o, 64);
            a2 += __shfl_xor(a2, o, 64);
            a3 += __shfl_xor(a3, o, 64);
            a4 += __shfl_xor(a4, o, 64);
            a5 += __shfl_xor(a5, o, 64);
        }
        if (lane < 3) {
            double l0, l1; const float* bb;
            if (lane == 0)      { l0 = a0; l1 = a1; bb = b1; }
            else if (lane == 1) { l0 = a2; l1 = a3; bb = b2; }
            else                { l0 = a4; l1 = a5; bb = b3; }
            bool valid = (lane == 0) || (lane == 1 && t < L_-1) || (lane == 2 && t < L_-2);
            float ev = 0.0f;
            if (valid) {
                l0 += (double)bb[0]; l1 += (double)bb[1];
                double m = fmax(l0, l1);
                double sa = l0 - m, sb = l1 - m;
                double lse = log(exp(sa) + exp(sb));
                float p0l = (float)(sa - lse), p1l = (float)(sb - lse);
                lph[lane*L_ + t] = make_float2(p0l, p1l);
                float p0 = expf(p0l), p1 = expf(p1l);
                ev = -(p0*p0l + p1*p1l) / LN2F;
            }
            entbuf[lane*L_ + t] = ev;
        }
    }

    cg::this_grid().sync();

    // ===== Phase A: per-sample masks -> LDS packed words; nll1 =====
    const int s = blockIdx.x;
    __shared__ uint64_t w1s[NW], w2s[NW], w3s[NW];
    __shared__ uint64_t o1s[NW], o2s[NW], o3s[NW];

    float2 lph2v[4], lph3v[4];
    float nllacc = 0.0f;
    #pragma unroll
    for (int it = 0; it < 4; it++) {
        const int t = it * 1024 + tid;
        float2 v1 = g1[(size_t)s * L_ + t];
        float2 p1v = lph[t];
        bool raw1 = (p1v.x + v1.x) >= (p1v.y + v1.y);   // argmax ties -> idx 0
        bool m1 = raw1 && (al1[t] != 0);
        nllacc += raw1 ? -p1v.x : -p1v.y;               // nll1: pre-align argmax
        bool m2 = false, m3 = false;
        lph2v[it] = make_float2(0.f, 0.f);
        lph3v[it] = make_float2(0.f, 0.f);
        if (t < L_-1) {
            float2 v2 = g2[(size_t)s * (L_-1) + t];
            float2 p2v = lph[L_ + t];
            lph2v[it] = p2v;
            m2 = ((p2v.x + v2.x) >= (p2v.y + v2.y)) && (al2[t] != 0);
        }
        if (t < L_-2) {
            float2 v3 = g3[(size_t)s * (L_-2) + t];
            float2 p3v = lph[2*L_ + t];
            lph3v[it] = p3v;
            m3 = ((p3v.x + v3.x) >= (p3v.y + v3.y)) && (al3[t] != 0);
        }
        unsigned long long b1b = __ballot(m1);
        unsigned long long b2b = __ballot(m2);
        unsigned long long b3b = __ballot(m3);
        if (lane == 0) {
            int w = t >> 6;
            w1s[w] = b1b; w2s[w] = b2b; w3s[w] = b3b;
        }
    }
    __syncthreads();

    // ===== Phase B: parallel conflict scan (wave 0, lane j owns word j) =====
    if (wv == 0) {
        const int j = lane;
        uint64_t w3w = w3s[j];
        uint64_t oA = pass1_noc(w3w);
        uint64_t oB = pass1_noc(w3w & ~1ull);
        unsigned F = (unsigned)(oA >> 63) | (((unsigned)(oB >> 63)) << 1);
        #pragma unroll
        for (int d = 1; d < 64; d <<= 1) {
            unsigned P = __shfl_up(F, d, 64);
            if (lane >= d) {
                unsigned la = P & 1, lb = (P >> 1) & 1;
                unsigned ra = F & 1, rb = (F >> 1) & 1;
                F = (la ? rb : ra) | ((lb ? rb : ra) << 1);
            }
        }
        unsigned Fp = __shfl_up(F, 1, 64);
        unsigned cin = (lane == 0) ? 0u : (Fp & 1);
        uint64_t p1 = cin ? oB : oA;

        uint64_t q0 = pass2_noc(p1);
        uint64_t q1 = pass2_noc(p1 & ~1ull);
        uint64_t q2 = pass2_noc(p1 & ~2ull);
        uint64_t q3 = pass2_noc(p1 & ~3ull);
        #define ST_(o) ((unsigned)(((o >> 62) & 1) | (((o >> 63) & 1) << 1)))
        unsigned G = ST_(q0) | (ST_(q1) << 2) | (ST_(q2) << 4) | (ST_(q3) << 6);
        #undef ST_
        #pragma unroll
        for (int d = 1; d < 64; d <<= 1) {
            unsigned P = __shfl_up(G, d, 64);
            if (lane >= d) {
                unsigned H = 0;
                #pragma unroll
                for (int xx = 0; xx < 4; xx++) {
                    unsigned m = (P >> (2 * xx)) & 3;
                    H |= ((G >> (2 * m)) & 3) << (2 * xx);
                }
                G = H;
            }
        }
        unsigned Gp = __shfl_up(G, 1, 64);
        unsigned s2in = (lane == 0) ? 0u : (Gp & 3);
        uint64_t B3 = (s2in == 0) ? q0 : (s2in == 1) ? q1 : (s2in == 2) ? q2 : q3;

        uint64_t B3m1 = __shfl_up((unsigned long long)B3, 1, 64); if (lane == 0)  B3m1 = 0;
        uint64_t B3nx = __shfl_down((unsigned long long)B3, 1, 64); if (lane == 63) B3nx = 0;
        uint64_t sh1 = (B3 << 1) | (B3m1 >> 63);
        uint64_t sh2 = (B3 << 2) | (B3m1 >> 62);
        uint64_t shm = (B3 >> 1) | (B3nx << 63);
        uint64_t hit2 = B3 | sh1 | sh2 | shm;

        uint64_t in2 = w2s[j] & ~hit2;
        uint64_t oA2 = pass1_noc(in2);
        uint64_t oB2 = pass1_noc(in2 & ~1ull);
        unsigned F2 = (unsigned)(oA2 >> 63) | (((unsigned)(oB2 >> 63)) << 1);
        #pragma unroll
        for (int d = 1; d < 64; d <<= 1) {
            unsigned P = __shfl_up(F2, d, 64);
            if (lane >= d) {
                unsigned la = P & 1, lb = (P >> 1) & 1;
                unsigned ra = F2 & 1, rb = (F2 >> 1) & 1;
                F2 = (la ? rb : ra) | ((lb ? rb : ra) << 1);
            }
        }
        unsigned F2p = __shfl_up(F2, 1, 64);
        unsigned cin2 = (lane == 0) ? 0u : (F2p & 1);
        uint64_t B2 = cin2 ? oB2 : oA2;

        uint64_t B2m1 = __shfl_up((unsigned long long)B2, 1, 64); if (lane == 0) B2m1 = 0;
        uint64_t hit1 = B3 | sh1 | sh2 | B2 | ((B2 << 1) | (B2m1 >> 63));
        uint64_t B1 = w1s[j] & ~hit1;

        o1s[j] = B1; o2s[j] = B2; o3s[j] = B3;
    }
    __syncthreads();

    // ===== Phase C: unpack + nll2/3 =====
    float* b1o = out + 2*S_;
    float* b2o = b1o + (size_t)S_ * L_;
    float* b3o = b2o + (size_t)S_ * (L_-1);
    #pragma unroll
    for (int it = 0; it < 4; it++) {
        const int t = it * 1024 + tid;
        const int w = t >> 6, b = t & 63;
        b1o[(size_t)s*L_ + t] = (float)((o1s[w] >> b) & 1);
        if (t < L_-1) {
            unsigned bit = (unsigned)((o2s[w] >> b) & 1);
            b2o[(size_t)s*(L_-1) + t] = (float)bit;
            nllacc += bit ? -lph2v[it].x : -lph2v[it].y;
        }
        if (t < L_-2) {
            unsigned bit = (unsigned)((o3s[w] >> b) & 1);
            b3o[(size_t)s*(L_-2) + t] = (float)bit;
            nllacc += bit ? -lph3v[it].x : -lph3v[it].y;
        }
    }
    #pragma unroll
    for (int o = 32; o > 0; o >>= 1) nllacc += __shfl_xor(nllacc, o, 64);
    __shared__ float red[16];
    if (lane == 0) red[wv] = nllacc;
    __syncthreads();
    if (tid == 0) {
        float tot = 0.f;
        #pragma unroll
        for (int i = 0; i < 16; i++) tot += red[i];
        out[S_ + s] = tot;
    }

    // ===== nent tail: block 0, wave 0 (entbuf visible since grid sync) =====
    if (s == 0 && wv == 0) {
        double s1 = 0, s2d = 0, s3d = 0;
        for (int t = lane; t < L_; t += 64) {
            s1  += (double)entbuf[t];
            s2d += (double)entbuf[L_ + t];
            s3d += (double)entbuf[2*L_ + t];
        }
        #pragma unroll
        for (int o = 32; o > 0; o >>= 1) {
            s1  += __shfl_xor(s1, o, 64);
            s2d += __shfl_xor(s2d, o, 64);
            s3d += __shfl_xor(s3d, o, 64);
        }
        float v = (float)((s1 / (double)L_ + s2d / (double)(L_-1) + s3d / (double)(L_-2)) / 3.0);
        #pragma unroll
        for (int i = 0; i < 4; i++) out[lane + 64*i] = v;
    }
}

extern "C" void kernel_launch(void* const* d_in, const int* in_sizes, int n_in,
                              void* d_out, int out_size, void* d_ws, size_t ws_size,
                              hipStream_t stream) {
    const int*   x    = (const int*)d_in[0];
    const int*   al1  = (const int*)d_in[2];
    const int*   al2  = (const int*)d_in[3];
    const int*   al3  = (const int*)d_in[4];
    const float* embd = (const float*)d_in[5];
    const float* w1   = (const float*)d_in[6];
    const float* b1   = (const float*)d_in[7];
    const float* w2   = (const float*)d_in[8];
    const float* b2   = (const float*)d_in[9];
    const float* w3   = (const float*)d_in[10];
    const float* b3   = (const float*)d_in[11];
    const float2* g1  = (const float2*)d_in[12];
    const float2* g2  = (const float2*)d_in[13];
    const float2* g3  = (const float2*)d_in[14];
    float* out = (float*)d_out;

    // ws layout: lph float2[3][4096] | entbuf float[3][4096]
    float2* lph   = (float2*)d_ws;
    float* entbuf = (float*)(lph + 3 * L_);

    void* args[] = {
        (void*)&x, (void*)&embd,
        (void*)&w1, (void*)&b1, (void*)&w2, (void*)&b2, (void*)&w3, (void*)&b3,
        (void*)&al1, (void*)&al2, (void*)&al3,
        (void*)&g1, (void*)&g2, (void*)&g3,
        (void*)&lph, (void*)&entbuf, (void*)&out
    };
    hipLaunchCooperativeKernel((const void*)k_all, dim3(S_), dim3(1024), args, 0, stream);
}

// Round 6
// 168.582 us; speedup vs baseline: 1.3200x; 1.3200x over previous
//
#include <hip/hip_runtime.h>
#include <stdint.h>

#define L_ 4096
#define S_ 256
#define D_ 512
#define NW 64  // 64-bit words per length-4096 row

static __device__ const float LN2F = 0.69314718055994530942f;

// ---------------- per-position logits -> logp (one wave per position) ----------------
__global__ __launch_bounds__(256)
void k_rows(const int* __restrict__ x, const float* __restrict__ embd,
            const float* __restrict__ w1, const float* __restrict__ b1,
            const float* __restrict__ w2, const float* __restrict__ b2,
            const float* __restrict__ w3, const float* __restrict__ b3,
            float2* __restrict__ lph, float* __restrict__ entbuf) {
    const int wid  = threadIdx.x >> 6;
    const int lane = threadIdx.x & 63;
    const int t = blockIdx.x * 4 + wid;           // grid 1024 -> t in [0,4096)
    const int t1 = (t + 1 < L_) ? t + 1 : t;
    const int t2 = (t + 2 < L_) ? t + 2 : t;
    const int d0 = lane * 8;

    const float4* e0p = (const float4*)(embd + (size_t)x[t]  * D_ + d0);
    const float4* e1p = (const float4*)(embd + (size_t)x[t1] * D_ + d0);
    const float4* e2p = (const float4*)(embd + (size_t)x[t2] * D_ + d0);
    float4 e0a = e0p[0], e0b = e0p[1];
    float4 e1a = e1p[0], e1b = e1p[1];
    float4 e2a = e2p[0], e2b = e2p[1];
    const float4* w1p = (const float4*)(w1 + 2 * d0);
    const float4* w2p = (const float4*)(w2 + 2 * d0);
    const float4* w3p = (const float4*)(w3 + 2 * d0);

    float v0[8] = {e0a.x,e0a.y,e0a.z,e0a.w,e0b.x,e0b.y,e0b.z,e0b.w};
    float v1[8] = {e1a.x,e1a.y,e1a.z,e1a.w,e1b.x,e1b.y,e1b.z,e1b.w};
    float v2[8] = {e2a.x,e2a.y,e2a.z,e2a.w,e2b.x,e2b.y,e2b.z,e2b.w};
    float wv1[16], wv2[16], wv3[16];
    for (int q = 0; q < 4; q++) {
        float4 a = w1p[q]; wv1[4*q]=a.x; wv1[4*q+1]=a.y; wv1[4*q+2]=a.z; wv1[4*q+3]=a.w;
        float4 b = w2p[q]; wv2[4*q]=b.x; wv2[4*q+1]=b.y; wv2[4*q+2]=b.z; wv2[4*q+3]=b.w;
        float4 c = w3p[q]; wv3[4*q]=c.x; wv3[4*q+1]=c.y; wv3[4*q+2]=c.z; wv3[4*q+3]=c.w;
    }
    double a0=0,a1=0,a2=0,a3=0,a4=0,a5=0;
    #pragma unroll
    for (int j = 0; j < 8; j++) {
        float s2 = (v1[j] + v0[j]) * 0.5f;        // reference order in f32
        float s3 = ((v2[j] + v1[j]) + v0[j]) / 3.0f;
        a0 += (double)v0[j] * (double)wv1[2*j];
        a1 += (double)v0[j] * (double)wv1[2*j+1];
        a2 += (double)s2    * (double)wv2[2*j];
        a3 += (double)s2    * (double)wv2[2*j+1];
        a4 += (double)s3    * (double)wv3[2*j];
        a5 += (double)s3    * (double)wv3[2*j+1];
    }
    #pragma unroll
    for (int o = 32; o > 0; o >>= 1) {
        a0 += __shfl_xor(a0, o, 64);
        a1 += __shfl_xor(a1, o, 64);
        a2 += __shfl_xor(a2, o, 64);
        a3 += __shfl_xor(a3, o, 64);
        a4 += __shfl_xor(a4, o, 64);
        a5 += __shfl_xor(a5, o, 64);
    }
    // lanes 0/1/2 each handle one head in parallel (all lanes hold all sums)
    if (lane < 3) {
        double l0, l1; const float* bb;
        if (lane == 0)      { l0 = a0; l1 = a1; bb = b1; }
        else if (lane == 1) { l0 = a2; l1 = a3; bb = b2; }
        else                { l0 = a4; l1 = a5; bb = b3; }
        bool valid = (lane == 0) || (lane == 1 && t < L_-1) || (lane == 2 && t < L_-2);
        float ev = 0.0f;
        if (valid) {
            l0 += (double)bb[0]; l1 += (double)bb[1];
            double m = fmax(l0, l1);
            double sa = l0 - m, sb = l1 - m;
            double lse = log(exp(sa) + exp(sb));
            float p0l = (float)(sa - lse), p1l = (float)(sb - lse);
            lph[lane*L_ + t] = make_float2(p0l, p1l);
            float p0 = expf(p0l), p1 = expf(p1l);
            ev = -(p0*p0l + p1*p1l) / LN2F;
        }
        entbuf[lane*L_ + t] = ev;
    }
}

// ---------------- word-local conflict primitives (no carry-in; caller masks) ----------------
// out[t] = c[t] & ~out[t-1] within a word, assuming out[-1]=0
__device__ __forceinline__ uint64_t pass1_noc(uint64_t wp) {
    uint64_t o = wp & ~(wp << 1);
    uint64_t h = wp & (wp << 1);
    o |= (o << 2)  & h; h &= (h << 2);
    o |= (o << 4)  & h; h &= (h << 4);
    o |= (o << 8)  & h; h &= (h << 8);
    o |= (o << 16) & h; h &= (h << 16);
    o |= (o << 32) & h;
    return o;
}
// out[t] = a[t] & ~out[t-2] within a word, assuming out[-1]=out[-2]=0
__device__ __forceinline__ uint64_t pass2_noc(uint64_t ap) {
    uint64_t o = ap & ~(ap << 2);
    uint64_t h = ap & (ap << 2);
    o |= (o << 4)  & h; h &= (h << 4);
    o |= (o << 8)  & h; h &= (h << 8);
    o |= (o << 16) & h; h &= (h << 16);
    o |= (o << 32) & h;
    return o;
}

// ---------------- fused: masks -> parallel LDS scan -> unpack + nll (+nent in blk0) ----------------
__global__ __launch_bounds__(1024)
void k_fused(const float2* __restrict__ lph,
             const int* __restrict__ al1, const int* __restrict__ al2, const int* __restrict__ al3,
             const float2* __restrict__ g1, const float2* __restrict__ g2, const float2* __restrict__ g3,
             const float* __restrict__ entbuf, float* __restrict__ out) {
    const int s = blockIdx.x;
    const int tid = threadIdx.x;
    const int lane = tid & 63;
    const int wv = tid >> 6;           // 0..15

    __shared__ uint64_t w1s[NW], w2s[NW], w3s[NW];
    __shared__ uint64_t o1s[NW], o2s[NW], o3s[NW];

    float2 lph2v[4], lph3v[4];
    float nllacc = 0.0f;
    #pragma unroll
    for (int it = 0; it < 4; it++) {
        const int t = it * 1024 + tid;
        float2 v1 = g1[(size_t)s * L_ + t];
        float2 p1v = lph[t];
        bool raw1 = (p1v.x + v1.x) >= (p1v.y + v1.y);   // argmax ties -> idx 0
        bool m1 = raw1 && (al1[t] != 0);
        nllacc += raw1 ? -p1v.x : -p1v.y;               // nll1: pre-align argmax
        bool m2 = false, m3 = false;
        lph2v[it] = make_float2(0.f, 0.f);
        lph3v[it] = make_float2(0.f, 0.f);
        if (t < L_-1) {
            float2 v2 = g2[(size_t)s * (L_-1) + t];
            float2 p2v = lph[L_ + t];
            lph2v[it] = p2v;
            m2 = ((p2v.x + v2.x) >= (p2v.y + v2.y)) && (al2[t] != 0);
        }
        if (t < L_-2) {
            float2 v3 = g3[(size_t)s * (L_-2) + t];
            float2 p3v = lph[2*L_ + t];
            lph3v[it] = p3v;
            m3 = ((p3v.x + v3.x) >= (p3v.y + v3.y)) && (al3[t] != 0);
        }
        unsigned long long b1b = __ballot(m1);
        unsigned long long b2b = __ballot(m2);
        unsigned long long b3b = __ballot(m3);
        if (lane == 0) {
            int w = t >> 6;
            w1s[w] = b1b; w2s[w] = b2b; w3s[w] = b3b;
        }
    }
    __syncthreads();

    // ---- parallel conflict scan: wave 0, lane j owns word j ----
    if (wv == 0) {
        const int j = lane;
        uint64_t w3w = w3s[j];
        uint64_t oA = pass1_noc(w3w);
        uint64_t oB = pass1_noc(w3w & ~1ull);
        unsigned F = (unsigned)(oA >> 63) | (((unsigned)(oB >> 63)) << 1);
        #pragma unroll
        for (int d = 1; d < 64; d <<= 1) {
            unsigned P = __shfl_up(F, d, 64);
            if (lane >= d) {
                unsigned la = P & 1, lb = (P >> 1) & 1;
                unsigned ra = F & 1, rb = (F >> 1) & 1;
                F = (la ? rb : ra) | ((lb ? rb : ra) << 1);
            }
        }
        unsigned Fp = __shfl_up(F, 1, 64);
        unsigned cin = (lane == 0) ? 0u : (Fp & 1);
        uint64_t p1 = cin ? oB : oA;

        uint64_t q0 = pass2_noc(p1);
        uint64_t q1 = pass2_noc(p1 & ~1ull);
        uint64_t q2 = pass2_noc(p1 & ~2ull);
        uint64_t q3 = pass2_noc(p1 & ~3ull);
        #define ST_(o) ((unsigned)(((o >> 62) & 1) | (((o >> 63) & 1) << 1)))
        unsigned G = ST_(q0) | (ST_(q1) << 2) | (ST_(q2) << 4) | (ST_(q3) << 6);
        #undef ST_
        #pragma unroll
        for (int d = 1; d < 64; d <<= 1) {
            unsigned P = __shfl_up(G, d, 64);
            if (lane >= d) {
                unsigned H = 0;
                #pragma unroll
                for (int xx = 0; xx < 4; xx++) {
                    unsigned m = (P >> (2 * xx)) & 3;
                    H |= ((G >> (2 * m)) & 3) << (2 * xx);
                }
                G = H;
            }
        }
        unsigned Gp = __shfl_up(G, 1, 64);
        unsigned s2in = (lane == 0) ? 0u : (Gp & 3);
        uint64_t B3 = (s2in == 0) ? q0 : (s2in == 1) ? q1 : (s2in == 2) ? q2 : q3;

        uint64_t B3m1 = __shfl_up((unsigned long long)B3, 1, 64); if (lane == 0)  B3m1 = 0;
        uint64_t B3nx = __shfl_down((unsigned long long)B3, 1, 64); if (lane == 63) B3nx = 0;
        uint64_t sh1 = (B3 << 1) | (B3m1 >> 63);
        uint64_t sh2 = (B3 << 2) | (B3m1 >> 62);
        uint64_t shm = (B3 >> 1) | (B3nx << 63);
        uint64_t hit2 = B3 | sh1 | sh2 | shm;

        uint64_t in2 = w2s[j] & ~hit2;
        uint64_t oA2 = pass1_noc(in2);
        uint64_t oB2 = pass1_noc(in2 & ~1ull);
        unsigned F2 = (unsigned)(oA2 >> 63) | (((unsigned)(oB2 >> 63)) << 1);
        #pragma unroll
        for (int d = 1; d < 64; d <<= 1) {
            unsigned P = __shfl_up(F2, d, 64);
            if (lane >= d) {
                unsigned la = P & 1, lb = (P >> 1) & 1;
                unsigned ra = F2 & 1, rb = (F2 >> 1) & 1;
                F2 = (la ? rb : ra) | ((lb ? rb : ra) << 1);
            }
        }
        unsigned F2p = __shfl_up(F2, 1, 64);
        unsigned cin2 = (lane == 0) ? 0u : (F2p & 1);
        uint64_t B2 = cin2 ? oB2 : oA2;

        uint64_t B2m1 = __shfl_up((unsigned long long)B2, 1, 64); if (lane == 0) B2m1 = 0;
        uint64_t hit1 = B3 | sh1 | sh2 | B2 | ((B2 << 1) | (B2m1 >> 63));
        uint64_t B1 = w1s[j] & ~hit1;

        o1s[j] = B1; o2s[j] = B2; o3s[j] = B3;
    }
    __syncthreads();

    float* b1o = out + 2*S_;
    float* b2o = b1o + (size_t)S_ * L_;
    float* b3o = b2o + (size_t)S_ * (L_-1);
    #pragma unroll
    for (int it = 0; it < 4; it++) {
        const int t = it * 1024 + tid;
        const int w = t >> 6, b = t & 63;
        b1o[(size_t)s*L_ + t] = (float)((o1s[w] >> b) & 1);
        if (t < L_-1) {
            unsigned bit = (unsigned)((o2s[w] >> b) & 1);
            b2o[(size_t)s*(L_-1) + t] = (float)bit;
            nllacc += bit ? -lph2v[it].x : -lph2v[it].y;
        }
        if (t < L_-2) {
            unsigned bit = (unsigned)((o3s[w] >> b) & 1);
            b3o[(size_t)s*(L_-2) + t] = (float)bit;
            nllacc += bit ? -lph3v[it].x : -lph3v[it].y;
        }
    }
    #pragma unroll
    for (int o = 32; o > 0; o >>= 1) nllacc += __shfl_xor(nllacc, o, 64);
    __shared__ float red[16];
    if (lane == 0) red[wv] = nllacc;
    __syncthreads();
    if (tid == 0) {
        float tot = 0.f;
        #pragma unroll
        for (int i = 0; i < 16; i++) tot += red[i];
        out[S_ + s] = tot;
    }

    // ---- nent tail: block 0, wave 0 only (entbuf ready from k_rows) ----
    if (s == 0 && wv == 0) {
        double s1 = 0, s2d = 0, s3d = 0;
        for (int t = lane; t < L_; t += 64) {
            s1  += (double)entbuf[t];
            s2d += (double)entbuf[L_ + t];
            s3d += (double)entbuf[2*L_ + t];
        }
        #pragma unroll
        for (int o = 32; o > 0; o >>= 1) {
            s1  += __shfl_xor(s1, o, 64);
            s2d += __shfl_xor(s2d, o, 64);
            s3d += __shfl_xor(s3d, o, 64);
        }
        float v = (float)((s1 / (double)L_ + s2d / (double)(L_-1) + s3d / (double)(L_-2)) / 3.0);
        #pragma unroll
        for (int i = 0; i < 4; i++) out[lane + 64*i] = v;
    }
}

extern "C" void kernel_launch(void* const* d_in, const int* in_sizes, int n_in,
                              void* d_out, int out_size, void* d_ws, size_t ws_size,
                              hipStream_t stream) {
    const int*   x    = (const int*)d_in[0];
    const int*   al1  = (const int*)d_in[2];
    const int*   al2  = (const int*)d_in[3];
    const int*   al3  = (const int*)d_in[4];
    const float* embd = (const float*)d_in[5];
    const float* w1   = (const float*)d_in[6];
    const float* b1   = (const float*)d_in[7];
    const float* w2   = (const float*)d_in[8];
    const float* b2   = (const float*)d_in[9];
    const float* w3   = (const float*)d_in[10];
    const float* b3   = (const float*)d_in[11];
    const float2* g1  = (const float2*)d_in[12];
    const float2* g2  = (const float2*)d_in[13];
    const float2* g3  = (const float2*)d_in[14];
    float* out = (float*)d_out;

    // ws layout: lph float2[3][4096] | entbuf float[3][4096]
    float2* lph   = (float2*)d_ws;
    float* entbuf = (float*)(lph + 3 * L_);

    hipLaunchKernelGGL(k_rows, dim3(1024), dim3(256), 0, stream,
                       x, embd, w1, b1, w2, b2, w3, b3, lph, entbuf);
    hipLaunchKernelGGL(k_fused, dim3(S_), dim3(1024), 0, stream,
                       lph, al1, al2, al3, g1, g2, g3, entbuf, out);
}

// Round 7
// 166.862 us; speedup vs baseline: 1.3336x; 1.0103x over previous
//
#include <hip/hip_runtime.h>
#include <stdint.h>

#define L_ 4096
#define S_ 256
#define D_ 512
#define NW 64  // 64-bit words per length-4096 row

static __device__ const float LN2F = 0.69314718055994530942f;

// ---------------- per-position logits -> logp (one wave per position) ----------------
__global__ __launch_bounds__(256)
void k_rows(const int* __restrict__ x, const float* __restrict__ embd,
            const float* __restrict__ w1, const float* __restrict__ b1,
            const float* __restrict__ w2, const float* __restrict__ b2,
            const float* __restrict__ w3, const float* __restrict__ b3,
            float2* __restrict__ lph, float* __restrict__ entbuf) {
    const int wid  = threadIdx.x >> 6;
    const int lane = threadIdx.x & 63;
    const int t = blockIdx.x * 4 + wid;           // grid 1024 -> t in [0,4096)
    const int t1 = (t + 1 < L_) ? t + 1 : t;
    const int t2 = (t + 2 < L_) ? t + 2 : t;
    const int d0 = lane * 8;

    const float4* e0p = (const float4*)(embd + (size_t)x[t]  * D_ + d0);
    const float4* e1p = (const float4*)(embd + (size_t)x[t1] * D_ + d0);
    const float4* e2p = (const float4*)(embd + (size_t)x[t2] * D_ + d0);
    float4 e0a = e0p[0], e0b = e0p[1];
    float4 e1a = e1p[0], e1b = e1p[1];
    float4 e2a = e2p[0], e2b = e2p[1];
    const float4* w1p = (const float4*)(w1 + 2 * d0);
    const float4* w2p = (const float4*)(w2 + 2 * d0);
    const float4* w3p = (const float4*)(w3 + 2 * d0);

    float v0[8] = {e0a.x,e0a.y,e0a.z,e0a.w,e0b.x,e0b.y,e0b.z,e0b.w};
    float v1[8] = {e1a.x,e1a.y,e1a.z,e1a.w,e1b.x,e1b.y,e1b.z,e1b.w};
    float v2[8] = {e2a.x,e2a.y,e2a.z,e2a.w,e2b.x,e2b.y,e2b.z,e2b.w};
    float wv1[16], wv2[16], wv3[16];
    for (int q = 0; q < 4; q++) {
        float4 a = w1p[q]; wv1[4*q]=a.x; wv1[4*q+1]=a.y; wv1[4*q+2]=a.z; wv1[4*q+3]=a.w;
        float4 b = w2p[q]; wv2[4*q]=b.x; wv2[4*q+1]=b.y; wv2[4*q+2]=b.z; wv2[4*q+3]=b.w;
        float4 c = w3p[q]; wv3[4*q]=c.x; wv3[4*q+1]=c.y; wv3[4*q+2]=c.z; wv3[4*q+3]=c.w;
    }
    double a0=0,a1=0,a2=0,a3=0,a4=0,a5=0;
    #pragma unroll
    for (int j = 0; j < 8; j++) {
        float s2 = (v1[j] + v0[j]) * 0.5f;        // reference order in f32
        float s3 = ((v2[j] + v1[j]) + v0[j]) / 3.0f;
        a0 += (double)v0[j] * (double)wv1[2*j];
        a1 += (double)v0[j] * (double)wv1[2*j+1];
        a2 += (double)s2    * (double)wv2[2*j];
        a3 += (double)s2    * (double)wv2[2*j+1];
        a4 += (double)s3    * (double)wv3[2*j];
        a5 += (double)s3    * (double)wv3[2*j+1];
    }
    #pragma unroll
    for (int o = 32; o > 0; o >>= 1) {
        a0 += __shfl_xor(a0, o, 64);
        a1 += __shfl_xor(a1, o, 64);
        a2 += __shfl_xor(a2, o, 64);
        a3 += __shfl_xor(a3, o, 64);
        a4 += __shfl_xor(a4, o, 64);
        a5 += __shfl_xor(a5, o, 64);
    }
    if (lane < 3) {
        double l0, l1; const float* bb;
        if (lane == 0)      { l0 = a0; l1 = a1; bb = b1; }
        else if (lane == 1) { l0 = a2; l1 = a3; bb = b2; }
        else                { l0 = a4; l1 = a5; bb = b3; }
        bool valid = (lane == 0) || (lane == 1 && t < L_-1) || (lane == 2 && t < L_-2);
        float ev = 0.0f;
        if (valid) {
            l0 += (double)bb[0]; l1 += (double)bb[1];
            double m = fmax(l0, l1);
            double sa = l0 - m, sb = l1 - m;
            double lse = log(exp(sa) + exp(sb));
            float p0l = (float)(sa - lse), p1l = (float)(sb - lse);
            lph[lane*L_ + t] = make_float2(p0l, p1l);
            float p0 = expf(p0l), p1 = expf(p1l);
            ev = -(p0*p0l + p1*p1l) / LN2F;
        }
        entbuf[lane*L_ + t] = ev;
    }
}

// ---------------- word-local conflict primitives ----------------
__device__ __forceinline__ uint64_t pass1_noc(uint64_t wp) {
    uint64_t o = wp & ~(wp << 1);
    uint64_t h = wp & (wp << 1);
    o |= (o << 2)  & h; h &= (h << 2);
    o |= (o << 4)  & h; h &= (h << 4);
    o |= (o << 8)  & h; h &= (h << 8);
    o |= (o << 16) & h; h &= (h << 16);
    o |= (o << 32) & h;
    return o;
}
__device__ __forceinline__ uint64_t pass2_noc(uint64_t ap) {
    uint64_t o = ap & ~(ap << 2);
    uint64_t h = ap & (ap << 2);
    o |= (o << 4)  & h; h &= (h << 4);
    o |= (o << 8)  & h; h &= (h << 8);
    o |= (o << 16) & h; h &= (h << 16);
    o |= (o << 32) & h;
    return o;
}
// spread low 32 bits to even positions
__device__ __forceinline__ uint64_t p1b1(uint64_t x) {
    x &= 0xFFFFFFFFull;
    x = (x | (x << 16)) & 0x0000FFFF0000FFFFull;
    x = (x | (x << 8))  & 0x00FF00FF00FF00FFull;
    x = (x | (x << 4))  & 0x0F0F0F0F0F0F0F0Full;
    x = (x | (x << 2))  & 0x3333333333333333ull;
    x = (x | (x << 1))  & 0x5555555555555555ull;
    return x;
}
__device__ __forceinline__ uint64_t shfl_u64(uint64_t v, int src) {
    return (uint64_t)__shfl((unsigned long long)v, src, 64);
}

// ---------------- fused: paired masks -> per-wave scan -> paired unpack ----------------
__global__ __launch_bounds__(1024)
void k_fused(const float2* __restrict__ lph,
             const int* __restrict__ al1, const int* __restrict__ al2, const int* __restrict__ al3,
             const float2* __restrict__ g1, const float2* __restrict__ g2, const float2* __restrict__ g3,
             const float* __restrict__ entbuf, float* __restrict__ out) {
    const int s = blockIdx.x;
    const int tid = threadIdx.x;
    const int lane = tid & 63;
    const int wv = tid >> 6;           // 0..15

    __shared__ uint64_t w1s[NW], w2s[NW], w3s[NW];

    const float2* g1s = g1 + (size_t)s * L_;
    const float2* g2s = g2 + (size_t)s * (L_-1);
    const float2* g3s = g3 + (size_t)s * (L_-2);

    float4 lp2v[2], lp3v[2];
    float nllacc = 0.0f;

    // ===== Phase A: each thread owns positions t=2q, 2q+1 =====
    #pragma unroll
    for (int it = 0; it < 2; it++) {
        const int q = it * 1024 + tid;          // 0..2047
        float4 gg1 = ((const float4*)g1s)[q];   // gumbel pairs for t0, t1
        float4 pp1 = ((const float4*)lph)[q];   // logp pairs for t0, t1
        int2   aa1 = ((const int2*)al1)[q];
        bool r1e = (pp1.x + gg1.x) >= (pp1.y + gg1.y);
        bool r1o = (pp1.z + gg1.z) >= (pp1.w + gg1.w);
        bool m1e = r1e && (aa1.x != 0);
        bool m1o = r1o && (aa1.y != 0);
        nllacc += (r1e ? -pp1.x : -pp1.y) + (r1o ? -pp1.z : -pp1.w);

        bool m2e = false, m2o = false, m3e = false, m3o = false;
        float4 p2 = make_float4(0.f,0.f,0.f,0.f), p3 = make_float4(0.f,0.f,0.f,0.f);
        if (q < 2047) {
            float2 ga = g2s[2*q], gb = g2s[2*q+1];      // odd row stride: scalar float2 x2
            p2 = ((const float4*)(lph + L_))[q];
            int2 aa2 = ((const int2*)al2)[q];
            m2e = ((p2.x + ga.x) >= (p2.y + ga.y)) && (aa2.x != 0);
            m2o = ((p2.z + gb.x) >= (p2.w + gb.y)) && (aa2.y != 0);
            float4 gg3 = ((const float4*)g3s)[q];
            p3 = ((const float4*)(lph + 2*L_))[q];
            int2 aa3 = ((const int2*)al3)[q];
            m3e = ((p3.x + gg3.x) >= (p3.y + gg3.y)) && (aa3.x != 0);
            m3o = ((p3.z + gg3.z) >= (p3.w + gg3.w)) && (aa3.y != 0);
        } else {
            // q==2047: t0=4094 (head2 valid), t1=4095 (none); head3 invalid
            float2 ga = g2s[4094];
            float2 pa = lph[L_ + 4094];
            p2 = make_float4(pa.x, pa.y, 0.f, 0.f);
            m2e = ((pa.x + ga.x) >= (pa.y + ga.y)) && (al2[4094] != 0);
        }
        lp2v[it] = p2; lp3v[it] = p3;

        uint64_t be1 = __ballot(m1e), bo1 = __ballot(m1o);
        uint64_t be2 = __ballot(m2e), bo2 = __ballot(m2o);
        uint64_t be3 = __ballot(m3e), bo3 = __ballot(m3o);
        // reconstruct t-ordered words: w0 covers lanes 0..31, w1 lanes 32..63
        const int w0i = it * 32 + wv * 2;
        if (lane == 0) {
            w1s[w0i] = p1b1(be1) | (p1b1(bo1) << 1);
            w2s[w0i] = p1b1(be2) | (p1b1(bo2) << 1);
            w3s[w0i] = p1b1(be3) | (p1b1(bo3) << 1);
        } else if (lane == 1) {
            w1s[w0i+1] = p1b1(be1 >> 32) | (p1b1(bo1 >> 32) << 1);
            w2s[w0i+1] = p1b1(be2 >> 32) | (p1b1(bo2 >> 32) << 1);
            w3s[w0i+1] = p1b1(be3 >> 32) | (p1b1(bo3 >> 32) << 1);
        }
    }
    __syncthreads();

    // ===== Phase B: conflict scan, redundantly in EVERY wave (lane j owns word j) =====
    const int j = lane;
    uint64_t w3w = w3s[j];
    uint64_t oA = pass1_noc(w3w);
    uint64_t oB = pass1_noc(w3w & ~1ull);
    unsigned F = (unsigned)(oA >> 63) | (((unsigned)(oB >> 63)) << 1);
    #pragma unroll
    for (int d = 1; d < 64; d <<= 1) {
        unsigned P = __shfl_up(F, d, 64);
        if (lane >= d) {
            unsigned la = P & 1, lb = (P >> 1) & 1;
            unsigned ra = F & 1, rb = (F >> 1) & 1;
            F = (la ? rb : ra) | ((lb ? rb : ra) << 1);
        }
    }
    unsigned Fp = __shfl_up(F, 1, 64);
    unsigned cin = (lane == 0) ? 0u : (Fp & 1);
    uint64_t p1w_ = cin ? oB : oA;

    uint64_t q0 = pass2_noc(p1w_);
    uint64_t q1 = pass2_noc(p1w_ & ~1ull);
    uint64_t q2 = pass2_noc(p1w_ & ~2ull);
    uint64_t q3 = pass2_noc(p1w_ & ~3ull);
    #define ST_(o) ((unsigned)(((o >> 62) & 1) | (((o >> 63) & 1) << 1)))
    unsigned G = ST_(q0) | (ST_(q1) << 2) | (ST_(q2) << 4) | (ST_(q3) << 6);
    #undef ST_
    #pragma unroll
    for (int d = 1; d < 64; d <<= 1) {
        unsigned P = __shfl_up(G, d, 64);
        if (lane >= d) {
            unsigned H = 0;
            #pragma unroll
            for (int xx = 0; xx < 4; xx++) {
                unsigned m = (P >> (2 * xx)) & 3;
                H |= ((G >> (2 * m)) & 3) << (2 * xx);
            }
            G = H;
        }
    }
    unsigned Gp = __shfl_up(G, 1, 64);
    unsigned s2in = (lane == 0) ? 0u : (Gp & 3);
    uint64_t B3 = (s2in == 0) ? q0 : (s2in == 1) ? q1 : (s2in == 2) ? q2 : q3;

    uint64_t B3m1 = shfl_u64(B3, lane - 1); if (lane == 0)  B3m1 = 0;
    uint64_t B3nx = shfl_u64(B3, lane + 1); if (lane == 63) B3nx = 0;
    uint64_t sh1 = (B3 << 1) | (B3m1 >> 63);
    uint64_t sh2 = (B3 << 2) | (B3m1 >> 62);
    uint64_t shm = (B3 >> 1) | (B3nx << 63);
    uint64_t hit2 = B3 | sh1 | sh2 | shm;

    uint64_t in2 = w2s[j] & ~hit2;
    uint64_t oA2 = pass1_noc(in2);
    uint64_t oB2 = pass1_noc(in2 & ~1ull);
    unsigned F2 = (unsigned)(oA2 >> 63) | (((unsigned)(oB2 >> 63)) << 1);
    #pragma unroll
    for (int d = 1; d < 64; d <<= 1) {
        unsigned P = __shfl_up(F2, d, 64);
        if (lane >= d) {
            unsigned la = P & 1, lb = (P >> 1) & 1;
            unsigned ra = F2 & 1, rb = (F2 >> 1) & 1;
            F2 = (la ? rb : ra) | ((lb ? rb : ra) << 1);
        }
    }
    unsigned F2p = __shfl_up(F2, 1, 64);
    unsigned cin2 = (lane == 0) ? 0u : (F2p & 1);
    uint64_t B2 = cin2 ? oB2 : oA2;

    uint64_t B2m1 = shfl_u64(B2, lane - 1); if (lane == 0) B2m1 = 0;
    uint64_t hit1 = B3 | sh1 | sh2 | B2 | ((B2 << 1) | (B2m1 >> 63));
    uint64_t B1 = w1s[j] & ~hit1;
    // no second barrier: each wave holds the full scan in registers

    // ===== Phase C: paired unpack via shuffle =====
    float2* b1r = (float2*)(out + 2*S_ + (size_t)s*L_);
    float*  b2r = out + 2*S_ + (size_t)S_*L_ + (size_t)s*(L_-1);
    float2* b3r = (float2*)(out + 2*S_ + (size_t)S_*L_ + (size_t)S_*(L_-1) + (size_t)s*(L_-2));
    #pragma unroll
    for (int it = 0; it < 2; it++) {
        const int q = it * 1024 + tid;
        const int widx = it * 32 + wv * 2 + (lane >> 5);
        const int bp = 2 * (lane & 31);
        uint64_t W1 = shfl_u64(B1, widx);
        uint64_t W2 = shfl_u64(B2, widx);
        uint64_t W3 = shfl_u64(B3, widx);
        unsigned v1e = (unsigned)(W1 >> bp) & 1, v1o = (unsigned)(W1 >> bp >> 1) & 1;
        unsigned v2e = (unsigned)(W2 >> bp) & 1, v2o = (unsigned)(W2 >> bp >> 1) & 1;
        unsigned v3e = (unsigned)(W3 >> bp) & 1, v3o = (unsigned)(W3 >> bp >> 1) & 1;
        b1r[q] = make_float2((float)v1e, (float)v1o);
        if (q < 2047) {
            b2r[2*q]   = (float)v2e;
            b2r[2*q+1] = (float)v2o;
            nllacc += (v2e ? -lp2v[it].x : -lp2v[it].y) + (v2o ? -lp2v[it].z : -lp2v[it].w);
            b3r[q] = make_float2((float)v3e, (float)v3o);
            nllacc += (v3e ? -lp3v[it].x : -lp3v[it].y) + (v3o ? -lp3v[it].z : -lp3v[it].w);
        } else {
            b2r[4094] = (float)v2e;
            nllacc += (v2e ? -lp2v[it].x : -lp2v[it].y);
        }
    }
    #pragma unroll
    for (int o = 32; o > 0; o >>= 1) nllacc += __shfl_xor(nllacc, o, 64);
    __shared__ float red[16];
    if (lane == 0) red[wv] = nllacc;
    __syncthreads();
    if (tid == 0) {
        float tot = 0.f;
        #pragma unroll
        for (int i = 0; i < 16; i++) tot += red[i];
        out[S_ + s] = tot;
    }

    // ---- nent tail: block 0, wave 0 ----
    if (s == 0 && wv == 0) {
        double s1 = 0, s2d = 0, s3d = 0;
        for (int t = lane; t < L_; t += 64) {
            s1  += (double)entbuf[t];
            s2d += (double)entbuf[L_ + t];
            s3d += (double)entbuf[2*L_ + t];
        }
        #pragma unroll
        for (int o = 32; o > 0; o >>= 1) {
            s1  += __shfl_xor(s1, o, 64);
            s2d += __shfl_xor(s2d, o, 64);
            s3d += __shfl_xor(s3d, o, 64);
        }
        float v = (float)((s1 / (double)L_ + s2d / (double)(L_-1) + s3d / (double)(L_-2)) / 3.0);
        #pragma unroll
        for (int i = 0; i < 4; i++) out[lane + 64*i] = v;
    }
}

extern "C" void kernel_launch(void* const* d_in, const int* in_sizes, int n_in,
                              void* d_out, int out_size, void* d_ws, size_t ws_size,
                              hipStream_t stream) {
    const int*   x    = (const int*)d_in[0];
    const int*   al1  = (const int*)d_in[2];
    const int*   al2  = (const int*)d_in[3];
    const int*   al3  = (const int*)d_in[4];
    const float* embd = (const float*)d_in[5];
    const float* w1   = (const float*)d_in[6];
    const float* b1   = (const float*)d_in[7];
    const float* w2   = (const float*)d_in[8];
    const float* b2   = (const float*)d_in[9];
    const float* w3   = (const float*)d_in[10];
    const float* b3   = (const float*)d_in[11];
    const float2* g1  = (const float2*)d_in[12];
    const float2* g2  = (const float2*)d_in[13];
    const float2* g3  = (const float2*)d_in[14];
    float* out = (float*)d_out;

    // ws layout: lph float2[3][4096] | entbuf float[3][4096]
    float2* lph   = (float2*)d_ws;
    float* entbuf = (float*)(lph + 3 * L_);

    hipLaunchKernelGGL(k_rows, dim3(1024), dim3(256), 0, stream,
                       x, embd, w1, b1, w2, b2, w3, b3, lph, entbuf);
    hipLaunchKernelGGL(k_fused, dim3(S_), dim3(1024), 0, stream,
                       lph, al1, al2, al3, g1, g2, g3, entbuf, out);
}